// Round 13
// baseline (112.643 us; speedup 1.0000x reference)
//
#include <hip/hip_runtime.h>
#include <hip/hip_fp16.h>
#include <stdint.h>

#define B_    200
#define N0    65536
#define COLS  (N0 * 3)
#define JT    64
#define TPAD2 228   // ushorts; 228*2=456B row stride, 8B-aligned for uint2 reads

__device__ static inline unsigned short f2h(float f) {
  __half h = __float2half(f);              // RNE
  return *reinterpret_cast<unsigned short*>(&h);
}
__device__ static inline float h2f(unsigned short u) {
  __half h = *reinterpret_cast<__half*>(&u);
  return __half2float(h);
}

// ---------------- Threefry-2x32 (JAX-compatible, 20 rounds) ----------------
__host__ __device__ static inline void tf2x32(uint32_t k0, uint32_t k1,
                                              uint32_t x0, uint32_t x1,
                                              uint32_t& o0, uint32_t& o1) {
  const uint32_t ks2 = k0 ^ k1 ^ 0x1BD11BDAu;
  x0 += k0; x1 += k1;
#define TF_R(r) { x0 += x1; x1 = (x1 << (r)) | (x1 >> (32 - (r))); x1 ^= x0; }
  TF_R(13) TF_R(15) TF_R(26) TF_R(6)   x0 += k1;  x1 += ks2 + 1u;
  TF_R(17) TF_R(29) TF_R(16) TF_R(24)  x0 += ks2; x1 += k0  + 2u;
  TF_R(13) TF_R(15) TF_R(26) TF_R(6)   x0 += k0;  x1 += k1  + 3u;
  TF_R(17) TF_R(29) TF_R(16) TF_R(24)  x0 += k1;  x1 += ks2 + 4u;
  TF_R(13) TF_R(15) TF_R(26) TF_R(6)   x0 += ks2; x1 += k0  + 5u;
#undef TF_R
  o0 = x0; o1 = x1;
}

__device__ static inline float drop_mask_apply(float hn, uint32_t b, uint32_t c,
                                               uint32_t nout, uint32_t k0, uint32_t k1) {
  uint32_t o0, o1;
  tf2x32(k0, k1, 0u, b * nout + c, o0, o1);
  uint32_t bits = o0 ^ o1;
  float u = __uint_as_float((bits >> 9) | 0x3f800000u) - 1.0f;
  return (u < 0.9f) ? hn * (1.0f / 0.9f) : 0.0f;
}

// ---------------- all row_ptrs in one kernel (+ zero KL slot) ----------------
__global__ void build_rp_all(const int* __restrict__ dst0, const int* __restrict__ dst1,
                             const int* __restrict__ dst2, const int* __restrict__ dst3,
                             const int* __restrict__ dst4,
                             int* rp0, int* rp1, int* rp2, int* rp3, int* rp4,
                             float* kl) {
  int tid = blockIdx.x * blockDim.x + threadIdx.x;
  if (tid == 0) *kl = 0.f;
  if (tid >= 21829) return;
  const int starts[6] = {0, 16385, 20482, 21507, 21764, 21829};
  const int EDGa[5]   = {147456, 36864, 9216, 2304, 576};
  const int* dsts[5]  = {dst0, dst1, dst2, dst3, dst4};
  int* rps[5]         = {rp0, rp1, rp2, rp3, rp4};
  int l = 0;
  while (tid >= starts[l + 1]) ++l;
  int c = tid - starts[l];
  const int* dst = dsts[l];
  int lo = 0, hi = EDGa[l];
  while (lo < hi) { int mid = (lo + hi) >> 1; if (dst[mid] < c) lo = mid + 1; else hi = mid; }
  rps[l][c] = lo;
}

// ---------------- KL over all 5 weight tensors, one kernel ----------------
__global__ __launch_bounds__(256) void kl_all_kernel(
    const float* __restrict__ w0, const float* __restrict__ w1,
    const float* __restrict__ w2, const float* __restrict__ w3,
    const float* __restrict__ w4, float* __restrict__ out) {
  __shared__ float red[256];
  const float* ws[5] = {w0, w1, w2, w3, w4};
  const int    ns[5] = {442368, 36864, 9216, 2304, 576};
  int stride = gridDim.x * blockDim.x;
  int tid0 = blockIdx.x * blockDim.x + threadIdx.x;
  float s = 0.f;
#pragma unroll
  for (int l = 0; l < 5; ++l) {
    const float* w = ws[l];
    int n = ns[l];
    for (int i = tid0; i < n; i += stride) {
      float v = w[i];
      s += fmaf(0.5f * v, v, 999.5f);      // 0.5*(w*w-1) - (-1000)
    }
  }
  red[threadIdx.x] = s;
  __syncthreads();
  for (int st = 128; st > 0; st >>= 1) {
    if (threadIdx.x < st) red[threadIdx.x] += red[threadIdx.x + st];
    __syncthreads();
  }
  if (threadIdx.x == 0) atomicAdd(out, red[0]);
}

// ---------------- transpose: 64 j-cols x ALL 200 b, fp16 LDS ----------------
// blockIdx swizzled so each XCD streams a contiguous 1/8 of j-space.
__global__ __launch_bounds__(512, 4) void transpose_rows_kernel(
    const float* __restrict__ x, unsigned short* __restrict__ xT2) {
  __shared__ unsigned short tile[JT * TPAD2];
  const int t  = threadIdx.x;              // 0..511
  const int nb = COLS / JT;                // 3072, divisible by 8
  const int bid = (int)blockIdx.x;
  const int sb  = (bid & 7) * (nb >> 3) + (bid >> 3);   // XCD-bijective swizzle
  const int j0 = sb * JT;
  const int tx = t & 15;                   // j-quad: cols 4tx..4tx+3
  const int bl = t >> 4;                   // 0..31

  const float* xp = x + j0 + (tx << 2);
  float4 v[7];
#pragma unroll
  for (int p = 0; p < 7; ++p) {
    int b = bl + (p << 5);
    b = b < B_ ? b : B_ - 1;               // clamp (only pass 6 clamps)
    v[p] = *(const float4*)(xp + (size_t)b * COLS);
  }
  __builtin_amdgcn_sched_barrier(0);       // loads stay ABOVE all LDS stores
#pragma unroll
  for (int p = 0; p < 7; ++p) {
    int b = bl + (p << 5);
    if (b < B_) {                          // compile-time true for p<6
      int base = (tx << 2) * TPAD2 + b;
      tile[base            ] = f2h(v[p].x);
      tile[base +     TPAD2] = f2h(v[p].y);
      tile[base + 2 * TPAD2] = f2h(v[p].z);
      tile[base + 3 * TPAD2] = f2h(v[p].w);
    }
  }
  __syncthreads();
  // 64 rows x 50 uint2 (8B = 4 fp16) = 3200 stores, dense 400B rows
#pragma unroll
  for (int q = 0; q < 7; ++q) {
    unsigned idx = (unsigned)t + ((unsigned)q << 9);
    if (idx < 3200u) {
      unsigned row = idx / 50u;            // magic-mul, unsigned
      unsigned g   = idx - row * 50u;
      uint2 o = *(const uint2*)&tile[row * TPAD2 + (g << 2)];
      *(uint2*)(xT2 + (size_t)(j0 + row) * B_ + (g << 2)) = o;
    }
  }
}

// ---------------- layer-1 pool + BN + ReLU + dropout ----------------
// 256 thr = 4 waves: 2 channels x 2 edge-halves.  Lane l<50 owns batches
// 4l..4l+3 via uint2 (8B) gathers -> 3 loads/edge.  One LDS combine +
// single barrier; BN stats via shfl butterfly; fp16 packed output.
__global__ __launch_bounds__(256) void pool1_bn_wave(
    const unsigned short* __restrict__ xT2, const int* __restrict__ src,
    const float* __restrict__ w, const float* __restrict__ bias,
    const int* __restrict__ rp, const float* __restrict__ gamma,
    const float* __restrict__ beta, unsigned short* __restrict__ out,
    uint32_t k0, uint32_t k1) {
  __shared__ float part[2][64][4];
  const int l    = threadIdx.x & 63;
  const int wid  = threadIdx.x >> 6;
  const int chl  = wid & 1;
  const int half = wid >> 1;
  const int c    = ((int)blockIdx.x << 1) + chl;
  const bool act = (l < 50);
  const int b4   = (act ? l : 0) << 2;     // batches b4..b4+3

  float a0 = 0.f, a1 = 0.f, a2 = 0.f, a3 = 0.f;
  const int e1 = rp[c + 1];
  int e = rp[c] + half;
#define P1_EDGE(EE)                                                          \
  {                                                                          \
    const unsigned short* base = xT2 + (size_t)src[EE] * (3 * B_) + b4;      \
    float w0 = w[3 * (EE)], w1 = w[3 * (EE) + 1], w2 = w[3 * (EE) + 2];      \
    uint2 p0 = *(const uint2*)(base);                                        \
    uint2 p1 = *(const uint2*)(base + B_);                                   \
    uint2 p2 = *(const uint2*)(base + 2 * B_);                               \
    a0 = fmaf(h2f((unsigned short)p0.x), w0, a0);                            \
    a1 = fmaf(h2f((unsigned short)(p0.x >> 16)), w0, a1);                    \
    a2 = fmaf(h2f((unsigned short)p0.y), w0, a2);                            \
    a3 = fmaf(h2f((unsigned short)(p0.y >> 16)), w0, a3);                    \
    a0 = fmaf(h2f((unsigned short)p1.x), w1, a0);                            \
    a1 = fmaf(h2f((unsigned short)(p1.x >> 16)), w1, a1);                    \
    a2 = fmaf(h2f((unsigned short)p1.y), w1, a2);                            \
    a3 = fmaf(h2f((unsigned short)(p1.y >> 16)), w1, a3);                    \
    a0 = fmaf(h2f((unsigned short)p2.x), w2, a0);                            \
    a1 = fmaf(h2f((unsigned short)(p2.x >> 16)), w2, a1);                    \
    a2 = fmaf(h2f((unsigned short)p2.y), w2, a2);                            \
    a3 = fmaf(h2f((unsigned short)(p2.y >> 16)), w2, a3);                    \
  }
  for (; e + 2 < e1; e += 4) { P1_EDGE(e) P1_EDGE(e + 2) }
  for (; e < e1; e += 2) { P1_EDGE(e) }
#undef P1_EDGE

  if (half == 1) {
    part[chl][l][0] = a0; part[chl][l][1] = a1;
    part[chl][l][2] = a2; part[chl][l][3] = a3;
  }
  __syncthreads();
  if (half == 1) return;
  a0 += part[chl][l][0]; a1 += part[chl][l][1];
  a2 += part[chl][l][2]; a3 += part[chl][l][3];
  const float bi = bias[c];
  a0 += bi; a1 += bi; a2 += bi; a3 += bi;
  if (!act) { a0 = a1 = a2 = a3 = 0.f; }

  float sv = a0 + a1 + a2 + a3;
  float qv = a0 * a0 + a1 * a1 + a2 * a2 + a3 * a3;
#pragma unroll
  for (int off = 32; off; off >>= 1) {
    sv += __shfl_xor(sv, off);
    qv += __shfl_xor(qv, off);
  }
  const float m   = sv * (1.f / 200.f);
  const float var = fmaf(qv, 1.f / 200.f, -m * m);
  const float scale = gamma[c] * rsqrtf(var + 1e-5f);
  const float shift = fmaf(-m, scale, beta[c]);

  if (act) {
    float r0 = drop_mask_apply(fmaxf(fmaf(a0, scale, shift), 0.f), (uint32_t)b4,      (uint32_t)c, 16384u, k0, k1);
    float r1 = drop_mask_apply(fmaxf(fmaf(a1, scale, shift), 0.f), (uint32_t)b4 + 1u, (uint32_t)c, 16384u, k0, k1);
    float r2 = drop_mask_apply(fmaxf(fmaf(a2, scale, shift), 0.f), (uint32_t)b4 + 2u, (uint32_t)c, 16384u, k0, k1);
    float r3 = drop_mask_apply(fmaxf(fmaf(a3, scale, shift), 0.f), (uint32_t)b4 + 3u, (uint32_t)c, 16384u, k0, k1);
    uint2 pk;
    pk.x = (uint32_t)f2h(r0) | ((uint32_t)f2h(r1) << 16);
    pk.y = (uint32_t)f2h(r2) | ((uint32_t)f2h(r3) << 16);
    *(uint2*)(out + (size_t)c * B_ + b4) = pk;
  }
}

// ---------------- layers 2..5: 2 waves/channel, uint2 gathers ----------------
__global__ __launch_bounds__(256) void pooln_wave(
    const unsigned short* __restrict__ hin, const int* __restrict__ src,
    const float* __restrict__ w, const float* __restrict__ bias,
    const int* __restrict__ rp, const float* __restrict__ gamma,
    const float* __restrict__ beta, void* __restrict__ outv,
    int nout, int has_bn, uint32_t k0, uint32_t k1) {
  __shared__ float part[2][64][4];
  const int l    = threadIdx.x & 63;
  const int wid  = threadIdx.x >> 6;
  const int chl  = wid & 1;
  const int half = wid >> 1;
  const int c    = ((int)blockIdx.x << 1) + chl;
  const bool act = (l < 50);
  const int b4   = (act ? l : 0) << 2;

  float a0 = 0.f, a1 = 0.f, a2 = 0.f, a3 = 0.f;
  const int e1 = rp[c + 1];
  int e = rp[c] + half;
#define PN_EDGE(EE)                                                          \
  {                                                                          \
    const unsigned short* base = hin + (size_t)src[EE] * B_ + b4;            \
    float we = w[EE];                                                        \
    uint2 p0 = *(const uint2*)(base);                                        \
    a0 = fmaf(h2f((unsigned short)p0.x), we, a0);                            \
    a1 = fmaf(h2f((unsigned short)(p0.x >> 16)), we, a1);                    \
    a2 = fmaf(h2f((unsigned short)p0.y), we, a2);                            \
    a3 = fmaf(h2f((unsigned short)(p0.y >> 16)), we, a3);                    \
  }
  for (; e + 2 < e1; e += 4) { PN_EDGE(e) PN_EDGE(e + 2) }
  for (; e < e1; e += 2) { PN_EDGE(e) }
#undef PN_EDGE

  if (half == 1) {
    part[chl][l][0] = a0; part[chl][l][1] = a1;
    part[chl][l][2] = a2; part[chl][l][3] = a3;
  }
  __syncthreads();
  if (half == 1) return;
  a0 += part[chl][l][0]; a1 += part[chl][l][1];
  a2 += part[chl][l][2]; a3 += part[chl][l][3];
  const float bi = bias[c];
  a0 += bi; a1 += bi; a2 += bi; a3 += bi;

  if (has_bn) {
    if (!act) { a0 = a1 = a2 = a3 = 0.f; }
    float sv = a0 + a1 + a2 + a3;
    float qv = a0 * a0 + a1 * a1 + a2 * a2 + a3 * a3;
#pragma unroll
    for (int off = 32; off; off >>= 1) {
      sv += __shfl_xor(sv, off);
      qv += __shfl_xor(qv, off);
    }
    const float m   = sv * (1.f / 200.f);
    const float var = fmaf(qv, 1.f / 200.f, -m * m);
    const float scale = gamma[c] * rsqrtf(var + 1e-5f);
    const float shift = fmaf(-m, scale, beta[c]);
    if (act) {
      unsigned short* out = (unsigned short*)outv;
      uint32_t no = (uint32_t)nout;
      float r0 = drop_mask_apply(fmaxf(fmaf(a0, scale, shift), 0.f), (uint32_t)b4,      (uint32_t)c, no, k0, k1);
      float r1 = drop_mask_apply(fmaxf(fmaf(a1, scale, shift), 0.f), (uint32_t)b4 + 1u, (uint32_t)c, no, k0, k1);
      float r2 = drop_mask_apply(fmaxf(fmaf(a2, scale, shift), 0.f), (uint32_t)b4 + 2u, (uint32_t)c, no, k0, k1);
      float r3 = drop_mask_apply(fmaxf(fmaf(a3, scale, shift), 0.f), (uint32_t)b4 + 3u, (uint32_t)c, no, k0, k1);
      uint2 pk;
      pk.x = (uint32_t)f2h(r0) | ((uint32_t)f2h(r1) << 16);
      pk.y = (uint32_t)f2h(r2) | ((uint32_t)f2h(r3) << 16);
      *(uint2*)(out + (size_t)c * B_ + b4) = pk;
    }
  } else if (act) {
    float* out = (float*)outv;             // (B, 64) f32 final output
    out[(size_t)(b4    ) * 64 + c] = a0;
    out[(size_t)(b4 + 1) * 64 + c] = a1;
    out[(size_t)(b4 + 2) * 64 + c] = a2;
    out[(size_t)(b4 + 3) * 64 + c] = a3;
  }
}

// ---------------- host ----------------
extern "C" void kernel_launch(void* const* d_in, const int* in_sizes, int n_in,
                              void* d_out, int out_size, void* d_ws, size_t ws_size,
                              hipStream_t stream) {
  (void)in_sizes; (void)n_in; (void)out_size; (void)ws_size;
  const float* x = (const float*)d_in[0];
  const int*   src[5]; const int* dst[5];
  const float* w[5];   const float* bias[5];
  const float* gamma[4]; const float* beta[4];
  int idx = 1;
  for (int l = 0; l < 5; ++l) {
    src[l]  = (const int*)d_in[idx++];
    dst[l]  = (const int*)d_in[idx++];
    w[l]    = (const float*)d_in[idx++];
    bias[l] = (const float*)d_in[idx++];
    if (l < 4) { gamma[l] = (const float*)d_in[idx++]; beta[l] = (const float*)d_in[idx++]; }
  }
  static const int NOUT[5] = {16384, 4096, 1024, 256, 64};

  // dkeys = jax.random.split(key(42), 4), partitionable threefry semantics
  uint32_t dk0[4], dk1[4];
  for (uint32_t i = 0; i < 4; ++i) tf2x32(0u, 42u, 0u, i, dk0[i], dk1[i]);

  // workspace carve
  char* ws = (char*)d_ws;
  size_t off = 0;
  auto carve = [&](size_t bytes) -> void* {
    void* p = ws + off;
    off = (off + bytes + 255) & ~(size_t)255;
    return p;
  };
  int* rp[5];
  for (int l = 0; l < 5; ++l) rp[l] = (int*)carve((size_t)(NOUT[l] + 1) * sizeof(int));
  unsigned short* h1 = (unsigned short*)carve((size_t)16384 * B_ * 2);
  unsigned short* h2 = (unsigned short*)carve((size_t)4096 * B_ * 2);
  unsigned short* h3 = (unsigned short*)carve((size_t)1024 * B_ * 2);
  unsigned short* h4 = (unsigned short*)carve((size_t)256 * B_ * 2);
  unsigned short* xT2 = (unsigned short*)carve((size_t)COLS * B_ * 2);

  float* kl = (float*)d_out + 12800;

  // 1: all row pointers + zero KL
  build_rp_all<<<(21829 + 255) / 256, 256, 0, stream>>>(
      dst[0], dst[1], dst[2], dst[3], dst[4],
      rp[0], rp[1], rp[2], rp[3], rp[4], kl);

  // 2: KL reduction (all layers)
  kl_all_kernel<<<256, 256, 0, stream>>>(w[0], w[1], w[2], w[3], w[4], kl);

  // 3: transpose -> fp16 xT (XCD-swizzled grid)
  transpose_rows_kernel<<<COLS / JT, 512, 0, stream>>>(x, xT2);

  // 4: layer 1 — 2 waves/channel -> fp16 h1
  pool1_bn_wave<<<16384 / 2, 256, 0, stream>>>(
      xT2, src[0], w[0], bias[0], rp[0], gamma[0], beta[0], h1,
      dk0[0], dk1[0]);

  // 5-8: layers 2..5 — 2 waves/channel, fp16 chain
  pooln_wave<<<4096 / 2, 256, 0, stream>>>(
      h1, src[1], w[1], bias[1], rp[1], gamma[1], beta[1], h2, 4096, 1,
      dk0[1], dk1[1]);
  pooln_wave<<<1024 / 2, 256, 0, stream>>>(
      h2, src[2], w[2], bias[2], rp[2], gamma[2], beta[2], h3, 1024, 1,
      dk0[2], dk1[2]);
  pooln_wave<<<256 / 2, 256, 0, stream>>>(
      h3, src[3], w[3], bias[3], rp[3], gamma[3], beta[3], h4, 256, 1,
      dk0[3], dk1[3]);
  pooln_wave<<<64 / 2, 256, 0, stream>>>(
      h4, src[4], w[4], bias[4], rp[4], nullptr, nullptr, (float*)d_out, 64, 0,
      0u, 0u);
}

// Round 14
// 105.912 us; speedup vs baseline: 1.0636x; 1.0636x over previous
//
#include <hip/hip_runtime.h>
#include <hip/hip_fp16.h>
#include <stdint.h>

#define B_    200
#define N0    65536
#define COLS  (N0 * 3)
#define JT    64
#define TPAD2 228   // ushorts; 228*2=456B row stride, 8B-aligned for uint2 reads

#define NTB   (COLS / JT)        // 3072 transpose blocks
#define RPB   43                 // row-ptr blocks (43*512 >= 21829)
#define KLB   64                 // KL reduction blocks

typedef float f32x4 __attribute__((ext_vector_type(4)));

__device__ static inline unsigned short f2h(float f) {
  __half h = __float2half(f);              // RNE
  return *reinterpret_cast<unsigned short*>(&h);
}
__device__ static inline float h2f(unsigned short u) {
  __half h = *reinterpret_cast<__half*>(&u);
  return __half2float(h);
}

// ---------------- Threefry-2x32 (JAX-compatible, 20 rounds) ----------------
__host__ __device__ static inline void tf2x32(uint32_t k0, uint32_t k1,
                                              uint32_t x0, uint32_t x1,
                                              uint32_t& o0, uint32_t& o1) {
  const uint32_t ks2 = k0 ^ k1 ^ 0x1BD11BDAu;
  x0 += k0; x1 += k1;
#define TF_R(r) { x0 += x1; x1 = (x1 << (r)) | (x1 >> (32 - (r))); x1 ^= x0; }
  TF_R(13) TF_R(15) TF_R(26) TF_R(6)   x0 += k1;  x1 += ks2 + 1u;
  TF_R(17) TF_R(29) TF_R(16) TF_R(24)  x0 += ks2; x1 += k0  + 2u;
  TF_R(13) TF_R(15) TF_R(26) TF_R(6)   x0 += k0;  x1 += k1  + 3u;
  TF_R(17) TF_R(29) TF_R(16) TF_R(24)  x0 += k1;  x1 += ks2 + 4u;
  TF_R(13) TF_R(15) TF_R(26) TF_R(6)   x0 += ks2; x1 += k0  + 5u;
#undef TF_R
  o0 = x0; o1 = x1;
}

__device__ static inline float drop_mask_apply(float hn, uint32_t b, uint32_t c,
                                               uint32_t nout, uint32_t k0, uint32_t k1) {
  uint32_t o0, o1;
  tf2x32(k0, k1, 0u, b * nout + c, o0, o1);
  uint32_t bits = o0 ^ o1;
  float u = __uint_as_float((bits >> 9) | 0x3f800000u) - 1.0f;
  return (u < 0.9f) ? hn * (1.0f / 0.9f) : 0.0f;
}

// ================= transpose + row-ptr + KL, one launch =================
// Blocks [0, NTB):       32x... wait, 64 j-cols x all 200 b transpose tile.
// Blocks [NTB, NTB+RPB): row_ptr binary searches (all 5 layers).
// Blocks [NTB+RPB, ...): KL reduction (atomicAdd into pre-zeroed kl).
__global__ __launch_bounds__(512, 4) void transpose_aux_kernel(
    const float* __restrict__ x, unsigned short* __restrict__ xT2,
    const int* __restrict__ dst0, const int* __restrict__ dst1,
    const int* __restrict__ dst2, const int* __restrict__ dst3,
    const int* __restrict__ dst4,
    int* __restrict__ rp0, int* __restrict__ rp1, int* __restrict__ rp2,
    int* __restrict__ rp3, int* __restrict__ rp4,
    const float* __restrict__ w0, const float* __restrict__ w1,
    const float* __restrict__ w2, const float* __restrict__ w3,
    const float* __restrict__ w4, float* __restrict__ kl) {
  __shared__ unsigned short tile[JT * TPAD2];
  const int bid = (int)blockIdx.x;
  const int t   = threadIdx.x;             // 0..511

  if (bid >= NTB) {
    if (bid < NTB + RPB) {
      // ---- row pointers ----
      int tid = (bid - NTB) * 512 + t;
      if (tid >= 21829) return;
      const int starts[6] = {0, 16385, 20482, 21507, 21764, 21829};
      const int EDGa[5]   = {147456, 36864, 9216, 2304, 576};
      const int* dsts[5]  = {dst0, dst1, dst2, dst3, dst4};
      int* rps[5]         = {rp0, rp1, rp2, rp3, rp4};
      int l = 0;
      while (tid >= starts[l + 1]) ++l;
      int c = tid - starts[l];
      const int* dst = dsts[l];
      int lo = 0, hi = EDGa[l];
      while (lo < hi) { int mid = (lo + hi) >> 1; if (dst[mid] < c) lo = mid + 1; else hi = mid; }
      rps[l][c] = lo;
    } else {
      // ---- KL reduction (kl pre-zeroed by hipMemsetAsync) ----
      float* red = (float*)tile;           // reuse LDS
      const float* ws[5] = {w0, w1, w2, w3, w4};
      const int    ns[5] = {442368, 36864, 9216, 2304, 576};
      const int stride = KLB * 512;
      const int tid0 = (bid - NTB - RPB) * 512 + t;
      float s = 0.f;
#pragma unroll
      for (int l = 0; l < 5; ++l) {
        const float* w = ws[l];
        int n = ns[l];
        for (int i = tid0; i < n; i += stride) {
          float v = w[i];
          s += fmaf(0.5f * v, v, 999.5f);  // 0.5*(w*w-1) - (-1000)
        }
      }
      red[t] = s;
      __syncthreads();
      for (int st = 256; st > 0; st >>= 1) {
        if (t < st) red[t] += red[t + st];
        __syncthreads();
      }
      if (t == 0) atomicAdd(kl, red[0]);
    }
    return;
  }

  // ---- transpose tile ----
  const int sb = (bid & 7) * (NTB >> 3) + (bid >> 3);   // XCD-bijective swizzle
  const int j0 = sb * JT;
  const int tx = t & 15;                   // j-quad: cols 4tx..4tx+3
  const int bl = t >> 4;                   // 0..31

  const float* xp = x + j0 + (tx << 2);
  const float* a0 = xp + (size_t)(bl      ) * COLS;
  const float* a1 = xp + (size_t)(bl +  32) * COLS;
  const float* a2 = xp + (size_t)(bl +  64) * COLS;
  const float* a3 = xp + (size_t)(bl +  96) * COLS;
  const float* a4 = xp + (size_t)(bl + 128) * COLS;
  const float* a5 = xp + (size_t)(bl + 160) * COLS;
  const int b6 = (bl + 192 < B_) ? bl + 192 : B_ - 1;   // clamp
  const float* a6 = xp + (size_t)b6 * COLS;

  // All 7 16B loads issued in one asm block, ONE vmcnt(0): forced MLP=7,
  // 28 VGPRs held live (compiler cannot re-serialize).
  f32x4 v0, v1, v2, v3, v4, v5, v6;
  asm volatile(
      "global_load_dwordx4 %0, %7, off\n\t"
      "global_load_dwordx4 %1, %8, off\n\t"
      "global_load_dwordx4 %2, %9, off\n\t"
      "global_load_dwordx4 %3, %10, off\n\t"
      "global_load_dwordx4 %4, %11, off\n\t"
      "global_load_dwordx4 %5, %12, off\n\t"
      "global_load_dwordx4 %6, %13, off\n\t"
      "s_waitcnt vmcnt(0)"
      : "=&v"(v0), "=&v"(v1), "=&v"(v2), "=&v"(v3), "=&v"(v4), "=&v"(v5), "=&v"(v6)
      : "v"(a0), "v"(a1), "v"(a2), "v"(a3), "v"(a4), "v"(a5), "v"(a6)
      : "memory");

  {
    const int base = (tx << 2) * TPAD2;
#define ST_ROW(VV, BB)                                                      \
    {                                                                       \
      int o = base + (BB);                                                  \
      tile[o            ] = f2h((VV)[0]);                                   \
      tile[o +     TPAD2] = f2h((VV)[1]);                                   \
      tile[o + 2 * TPAD2] = f2h((VV)[2]);                                   \
      tile[o + 3 * TPAD2] = f2h((VV)[3]);                                   \
    }
    ST_ROW(v0, bl)
    ST_ROW(v1, bl + 32)
    ST_ROW(v2, bl + 64)
    ST_ROW(v3, bl + 96)
    ST_ROW(v4, bl + 128)
    ST_ROW(v5, bl + 160)
    if (bl < 8) ST_ROW(v6, bl + 192)
#undef ST_ROW
  }
  __syncthreads();
  // 64 rows x 50 uint2 (8B = 4 fp16) = 3200 stores, dense 400B rows
#pragma unroll
  for (int q = 0; q < 7; ++q) {
    unsigned idx = (unsigned)t + ((unsigned)q << 9);
    if (idx < 3200u) {
      unsigned row = idx / 50u;            // magic-mul, unsigned
      unsigned g   = idx - row * 50u;
      uint2 o = *(const uint2*)&tile[row * TPAD2 + (g << 2)];
      *(uint2*)(xT2 + (size_t)(j0 + row) * B_ + (g << 2)) = o;
    }
  }
}

// ---------------- layer-1 pool + BN + ReLU + dropout ----------------
// 256 thr = 4 waves: 2 channels x 2 edge-halves.  Lane l<50 owns batches
// 4l..4l+3 via uint2 (8B) gathers -> 3 loads/edge.  One LDS combine +
// single barrier; BN stats via shfl butterfly; fp16 packed output.
__global__ __launch_bounds__(256) void pool1_bn_wave(
    const unsigned short* __restrict__ xT2, const int* __restrict__ src,
    const float* __restrict__ w, const float* __restrict__ bias,
    const int* __restrict__ rp, const float* __restrict__ gamma,
    const float* __restrict__ beta, unsigned short* __restrict__ out,
    uint32_t k0, uint32_t k1) {
  __shared__ float part[2][64][4];
  const int l    = threadIdx.x & 63;
  const int wid  = threadIdx.x >> 6;
  const int chl  = wid & 1;
  const int half = wid >> 1;
  const int c    = ((int)blockIdx.x << 1) + chl;
  const bool act = (l < 50);
  const int b4   = (act ? l : 0) << 2;     // batches b4..b4+3

  float a0 = 0.f, a1 = 0.f, a2 = 0.f, a3 = 0.f;
  const int e1 = rp[c + 1];
  int e = rp[c] + half;
#define P1_EDGE(EE)                                                          \
  {                                                                          \
    const unsigned short* base = xT2 + (size_t)src[EE] * (3 * B_) + b4;      \
    float w0 = w[3 * (EE)], w1 = w[3 * (EE) + 1], w2 = w[3 * (EE) + 2];      \
    uint2 p0 = *(const uint2*)(base);                                        \
    uint2 p1 = *(const uint2*)(base + B_);                                   \
    uint2 p2 = *(const uint2*)(base + 2 * B_);                               \
    a0 = fmaf(h2f((unsigned short)p0.x), w0, a0);                            \
    a1 = fmaf(h2f((unsigned short)(p0.x >> 16)), w0, a1);                    \
    a2 = fmaf(h2f((unsigned short)p0.y), w0, a2);                            \
    a3 = fmaf(h2f((unsigned short)(p0.y >> 16)), w0, a3);                    \
    a0 = fmaf(h2f((unsigned short)p1.x), w1, a0);                            \
    a1 = fmaf(h2f((unsigned short)(p1.x >> 16)), w1, a1);                    \
    a2 = fmaf(h2f((unsigned short)p1.y), w1, a2);                            \
    a3 = fmaf(h2f((unsigned short)(p1.y >> 16)), w1, a3);                    \
    a0 = fmaf(h2f((unsigned short)p2.x), w2, a0);                            \
    a1 = fmaf(h2f((unsigned short)(p2.x >> 16)), w2, a1);                    \
    a2 = fmaf(h2f((unsigned short)p2.y), w2, a2);                            \
    a3 = fmaf(h2f((unsigned short)(p2.y >> 16)), w2, a3);                    \
  }
  for (; e + 2 < e1; e += 4) { P1_EDGE(e) P1_EDGE(e + 2) }
  for (; e < e1; e += 2) { P1_EDGE(e) }
#undef P1_EDGE

  if (half == 1) {
    part[chl][l][0] = a0; part[chl][l][1] = a1;
    part[chl][l][2] = a2; part[chl][l][3] = a3;
  }
  __syncthreads();
  if (half == 1) return;
  a0 += part[chl][l][0]; a1 += part[chl][l][1];
  a2 += part[chl][l][2]; a3 += part[chl][l][3];
  const float bi = bias[c];
  a0 += bi; a1 += bi; a2 += bi; a3 += bi;
  if (!act) { a0 = a1 = a2 = a3 = 0.f; }

  float sv = a0 + a1 + a2 + a3;
  float qv = a0 * a0 + a1 * a1 + a2 * a2 + a3 * a3;
#pragma unroll
  for (int off = 32; off; off >>= 1) {
    sv += __shfl_xor(sv, off);
    qv += __shfl_xor(qv, off);
  }
  const float m   = sv * (1.f / 200.f);
  const float var = fmaf(qv, 1.f / 200.f, -m * m);
  const float scale = gamma[c] * rsqrtf(var + 1e-5f);
  const float shift = fmaf(-m, scale, beta[c]);

  if (act) {
    float r0 = drop_mask_apply(fmaxf(fmaf(a0, scale, shift), 0.f), (uint32_t)b4,      (uint32_t)c, 16384u, k0, k1);
    float r1 = drop_mask_apply(fmaxf(fmaf(a1, scale, shift), 0.f), (uint32_t)b4 + 1u, (uint32_t)c, 16384u, k0, k1);
    float r2 = drop_mask_apply(fmaxf(fmaf(a2, scale, shift), 0.f), (uint32_t)b4 + 2u, (uint32_t)c, 16384u, k0, k1);
    float r3 = drop_mask_apply(fmaxf(fmaf(a3, scale, shift), 0.f), (uint32_t)b4 + 3u, (uint32_t)c, 16384u, k0, k1);
    uint2 pk;
    pk.x = (uint32_t)f2h(r0) | ((uint32_t)f2h(r1) << 16);
    pk.y = (uint32_t)f2h(r2) | ((uint32_t)f2h(r3) << 16);
    *(uint2*)(out + (size_t)c * B_ + b4) = pk;
  }
}

// ---------------- layers 2..5: 2 waves/channel, uint2 gathers ----------------
__global__ __launch_bounds__(256) void pooln_wave(
    const unsigned short* __restrict__ hin, const int* __restrict__ src,
    const float* __restrict__ w, const float* __restrict__ bias,
    const int* __restrict__ rp, const float* __restrict__ gamma,
    const float* __restrict__ beta, void* __restrict__ outv,
    int nout, int has_bn, uint32_t k0, uint32_t k1) {
  __shared__ float part[2][64][4];
  const int l    = threadIdx.x & 63;
  const int wid  = threadIdx.x >> 6;
  const int chl  = wid & 1;
  const int half = wid >> 1;
  const int c    = ((int)blockIdx.x << 1) + chl;
  const bool act = (l < 50);
  const int b4   = (act ? l : 0) << 2;

  float a0 = 0.f, a1 = 0.f, a2 = 0.f, a3 = 0.f;
  const int e1 = rp[c + 1];
  int e = rp[c] + half;
#define PN_EDGE(EE)                                                          \
  {                                                                          \
    const unsigned short* base = hin + (size_t)src[EE] * B_ + b4;            \
    float we = w[EE];                                                        \
    uint2 p0 = *(const uint2*)(base);                                        \
    a0 = fmaf(h2f((unsigned short)p0.x), we, a0);                            \
    a1 = fmaf(h2f((unsigned short)(p0.x >> 16)), we, a1);                    \
    a2 = fmaf(h2f((unsigned short)p0.y), we, a2);                            \
    a3 = fmaf(h2f((unsigned short)(p0.y >> 16)), we, a3);                    \
  }
  for (; e + 2 < e1; e += 4) { PN_EDGE(e) PN_EDGE(e + 2) }
  for (; e < e1; e += 2) { PN_EDGE(e) }
#undef PN_EDGE

  if (half == 1) {
    part[chl][l][0] = a0; part[chl][l][1] = a1;
    part[chl][l][2] = a2; part[chl][l][3] = a3;
  }
  __syncthreads();
  if (half == 1) return;
  a0 += part[chl][l][0]; a1 += part[chl][l][1];
  a2 += part[chl][l][2]; a3 += part[chl][l][3];
  const float bi = bias[c];
  a0 += bi; a1 += bi; a2 += bi; a3 += bi;

  if (has_bn) {
    if (!act) { a0 = a1 = a2 = a3 = 0.f; }
    float sv = a0 + a1 + a2 + a3;
    float qv = a0 * a0 + a1 * a1 + a2 * a2 + a3 * a3;
#pragma unroll
    for (int off = 32; off; off >>= 1) {
      sv += __shfl_xor(sv, off);
      qv += __shfl_xor(qv, off);
    }
    const float m   = sv * (1.f / 200.f);
    const float var = fmaf(qv, 1.f / 200.f, -m * m);
    const float scale = gamma[c] * rsqrtf(var + 1e-5f);
    const float shift = fmaf(-m, scale, beta[c]);
    if (act) {
      unsigned short* out = (unsigned short*)outv;
      uint32_t no = (uint32_t)nout;
      float r0 = drop_mask_apply(fmaxf(fmaf(a0, scale, shift), 0.f), (uint32_t)b4,      (uint32_t)c, no, k0, k1);
      float r1 = drop_mask_apply(fmaxf(fmaf(a1, scale, shift), 0.f), (uint32_t)b4 + 1u, (uint32_t)c, no, k0, k1);
      float r2 = drop_mask_apply(fmaxf(fmaf(a2, scale, shift), 0.f), (uint32_t)b4 + 2u, (uint32_t)c, no, k0, k1);
      float r3 = drop_mask_apply(fmaxf(fmaf(a3, scale, shift), 0.f), (uint32_t)b4 + 3u, (uint32_t)c, no, k0, k1);
      uint2 pk;
      pk.x = (uint32_t)f2h(r0) | ((uint32_t)f2h(r1) << 16);
      pk.y = (uint32_t)f2h(r2) | ((uint32_t)f2h(r3) << 16);
      *(uint2*)(out + (size_t)c * B_ + b4) = pk;
    }
  } else if (act) {
    float* out = (float*)outv;             // (B, 64) f32 final output
    out[(size_t)(b4    ) * 64 + c] = a0;
    out[(size_t)(b4 + 1) * 64 + c] = a1;
    out[(size_t)(b4 + 2) * 64 + c] = a2;
    out[(size_t)(b4 + 3) * 64 + c] = a3;
  }
}

// ---------------- host ----------------
extern "C" void kernel_launch(void* const* d_in, const int* in_sizes, int n_in,
                              void* d_out, int out_size, void* d_ws, size_t ws_size,
                              hipStream_t stream) {
  (void)in_sizes; (void)n_in; (void)out_size; (void)ws_size;
  const float* x = (const float*)d_in[0];
  const int*   src[5]; const int* dst[5];
  const float* w[5];   const float* bias[5];
  const float* gamma[4]; const float* beta[4];
  int idx = 1;
  for (int l = 0; l < 5; ++l) {
    src[l]  = (const int*)d_in[idx++];
    dst[l]  = (const int*)d_in[idx++];
    w[l]    = (const float*)d_in[idx++];
    bias[l] = (const float*)d_in[idx++];
    if (l < 4) { gamma[l] = (const float*)d_in[idx++]; beta[l] = (const float*)d_in[idx++]; }
  }
  static const int NOUT[5] = {16384, 4096, 1024, 256, 64};

  // dkeys = jax.random.split(key(42), 4), partitionable threefry semantics
  uint32_t dk0[4], dk1[4];
  for (uint32_t i = 0; i < 4; ++i) tf2x32(0u, 42u, 0u, i, dk0[i], dk1[i]);

  // workspace carve
  char* ws = (char*)d_ws;
  size_t off = 0;
  auto carve = [&](size_t bytes) -> void* {
    void* p = ws + off;
    off = (off + bytes + 255) & ~(size_t)255;
    return p;
  };
  int* rp[5];
  for (int l = 0; l < 5; ++l) rp[l] = (int*)carve((size_t)(NOUT[l] + 1) * sizeof(int));
  unsigned short* h1 = (unsigned short*)carve((size_t)16384 * B_ * 2);
  unsigned short* h2 = (unsigned short*)carve((size_t)4096 * B_ * 2);
  unsigned short* h3 = (unsigned short*)carve((size_t)1024 * B_ * 2);
  unsigned short* h4 = (unsigned short*)carve((size_t)256 * B_ * 2);
  unsigned short* xT2 = (unsigned short*)carve((size_t)COLS * B_ * 2);

  float* kl = (float*)d_out + 12800;

  // 0: zero the KL accumulator (graph-capture-safe async memset)
  hipMemsetAsync(kl, 0, sizeof(float), stream);

  // 1: transpose + row-ptrs + KL in one launch
  transpose_aux_kernel<<<NTB + RPB + KLB, 512, 0, stream>>>(
      x, xT2,
      dst[0], dst[1], dst[2], dst[3], dst[4],
      rp[0], rp[1], rp[2], rp[3], rp[4],
      w[0], w[1], w[2], w[3], w[4], kl);

  // 2: layer 1 — 2 waves/channel -> fp16 h1
  pool1_bn_wave<<<16384 / 2, 256, 0, stream>>>(
      xT2, src[0], w[0], bias[0], rp[0], gamma[0], beta[0], h1,
      dk0[0], dk1[0]);

  // 3-6: layers 2..5 — 2 waves/channel, fp16 chain
  pooln_wave<<<4096 / 2, 256, 0, stream>>>(
      h1, src[1], w[1], bias[1], rp[1], gamma[1], beta[1], h2, 4096, 1,
      dk0[1], dk1[1]);
  pooln_wave<<<1024 / 2, 256, 0, stream>>>(
      h2, src[2], w[2], bias[2], rp[2], gamma[2], beta[2], h3, 1024, 1,
      dk0[2], dk1[2]);
  pooln_wave<<<256 / 2, 256, 0, stream>>>(
      h3, src[3], w[3], bias[3], rp[3], gamma[3], beta[3], h4, 256, 1,
      dk0[3], dk1[3]);
  pooln_wave<<<64 / 2, 256, 0, stream>>>(
      h4, src[4], w[4], bias[4], rp[4], nullptr, nullptr, (float*)d_out, 64, 0,
      0u, 0u);
}

// Round 15
// 105.510 us; speedup vs baseline: 1.0676x; 1.0038x over previous
//
#include <hip/hip_runtime.h>
#include <hip/hip_fp16.h>
#include <stdint.h>

#define B_    200
#define N0    65536
#define COLS  (N0 * 3)
#define JT    128
#define TPADS 232                // swizzled col space: max (199^31)=216 < 232

#define NTB   (COLS / JT)        // 1536 transpose blocks (divisible by 8)
#define RPB   43                 // row-ptr blocks (43*512 >= 21829)
#define KLB   64                 // KL reduction blocks

typedef float f32x4 __attribute__((ext_vector_type(4)));

__device__ static inline unsigned short f2h(float f) {
  __half h = __float2half(f);              // RNE
  return *reinterpret_cast<unsigned short*>(&h);
}
__device__ static inline float h2f(unsigned short u) {
  __half h = *reinterpret_cast<__half*>(&u);
  return __half2float(h);
}

// ---------------- Threefry-2x32 (JAX-compatible, 20 rounds) ----------------
__host__ __device__ static inline void tf2x32(uint32_t k0, uint32_t k1,
                                              uint32_t x0, uint32_t x1,
                                              uint32_t& o0, uint32_t& o1) {
  const uint32_t ks2 = k0 ^ k1 ^ 0x1BD11BDAu;
  x0 += k0; x1 += k1;
#define TF_R(r) { x0 += x1; x1 = (x1 << (r)) | (x1 >> (32 - (r))); x1 ^= x0; }
  TF_R(13) TF_R(15) TF_R(26) TF_R(6)   x0 += k1;  x1 += ks2 + 1u;
  TF_R(17) TF_R(29) TF_R(16) TF_R(24)  x0 += ks2; x1 += k0  + 2u;
  TF_R(13) TF_R(15) TF_R(26) TF_R(6)   x0 += k0;  x1 += k1  + 3u;
  TF_R(17) TF_R(29) TF_R(16) TF_R(24)  x0 += k1;  x1 += ks2 + 4u;
  TF_R(13) TF_R(15) TF_R(26) TF_R(6)   x0 += ks2; x1 += k0  + 5u;
#undef TF_R
  o0 = x0; o1 = x1;
}

__device__ static inline float drop_mask_apply(float hn, uint32_t b, uint32_t c,
                                               uint32_t nout, uint32_t k0, uint32_t k1) {
  uint32_t o0, o1;
  tf2x32(k0, k1, 0u, b * nout + c, o0, o1);
  uint32_t bits = o0 ^ o1;
  float u = __uint_as_float((bits >> 9) | 0x3f800000u) - 1.0f;
  return (u < 0.9f) ? hn * (1.0f / 0.9f) : 0.0f;
}

// ================= transpose + row-ptr + KL, one launch =================
// Transpose block: 128 j-cols x all 200 b.  512B read streak per row.
// LDS tile fp16 with XOR swizzle col' = b ^ (j>>2): write phase conflict-free
// (64 lanes -> 32 banks, dword-pair sharing), read phase unswizzles.
// 58KB LDS -> 2 blocks/CU (phase overlap across blocks).
__global__ __launch_bounds__(512, 4) void transpose_aux_kernel(
    const float* __restrict__ x, unsigned short* __restrict__ xT2,
    const int* __restrict__ dst0, const int* __restrict__ dst1,
    const int* __restrict__ dst2, const int* __restrict__ dst3,
    const int* __restrict__ dst4,
    int* __restrict__ rp0, int* __restrict__ rp1, int* __restrict__ rp2,
    int* __restrict__ rp3, int* __restrict__ rp4,
    const float* __restrict__ w0, const float* __restrict__ w1,
    const float* __restrict__ w2, const float* __restrict__ w3,
    const float* __restrict__ w4, float* __restrict__ kl) {
  __shared__ unsigned short tile[JT * TPADS];
  const int bid = (int)blockIdx.x;
  const int t   = threadIdx.x;             // 0..511

  if (bid >= NTB) {
    if (bid < NTB + RPB) {
      // ---- row pointers ----
      int tid = (bid - NTB) * 512 + t;
      if (tid >= 21829) return;
      const int starts[6] = {0, 16385, 20482, 21507, 21764, 21829};
      const int EDGa[5]   = {147456, 36864, 9216, 2304, 576};
      const int* dsts[5]  = {dst0, dst1, dst2, dst3, dst4};
      int* rps[5]         = {rp0, rp1, rp2, rp3, rp4};
      int l = 0;
      while (tid >= starts[l + 1]) ++l;
      int c = tid - starts[l];
      const int* dst = dsts[l];
      int lo = 0, hi = EDGa[l];
      while (lo < hi) { int mid = (lo + hi) >> 1; if (dst[mid] < c) lo = mid + 1; else hi = mid; }
      rps[l][c] = lo;
    } else {
      // ---- KL reduction (kl pre-zeroed by hipMemsetAsync) ----
      float* red = (float*)tile;           // reuse LDS
      const float* ws[5] = {w0, w1, w2, w3, w4};
      const int    ns[5] = {442368, 36864, 9216, 2304, 576};
      const int stride = KLB * 512;
      const int tid0 = (bid - NTB - RPB) * 512 + t;
      float s = 0.f;
#pragma unroll
      for (int l = 0; l < 5; ++l) {
        const float* w = ws[l];
        int n = ns[l];
        for (int i = tid0; i < n; i += stride) {
          float v = w[i];
          s += fmaf(0.5f * v, v, 999.5f);  // 0.5*(w*w-1) - (-1000)
        }
      }
      red[t] = s;
      __syncthreads();
      for (int st = 256; st > 0; st >>= 1) {
        if (t < st) red[t] += red[t + st];
        __syncthreads();
      }
      if (t == 0) atomicAdd(kl, red[0]);
    }
    return;
  }

  // ---- transpose tile ----
  const int sb = (bid & 7) * (NTB >> 3) + (bid >> 3);   // XCD-bijective swizzle
  const int j0 = sb * JT;
  const int tx = t & 31;                   // j-quad: cols 4tx..4tx+3
  const int bl = t >> 5;                   // 0..15

  const float* xp = x + j0 + (tx << 2);

  // 13 row-passes: b = bl + 16p (p=0..12; p=12 clamps for bl>=8).
  // 5-load asm groups: forced loads-in-flight, one vmcnt per group.
#define LOAD5(V0, V1, V2, V3, V4, P0, P1, P2, P3, P4)                        \
  asm volatile(                                                              \
      "global_load_dwordx4 %0, %5, off\n\t"                                  \
      "global_load_dwordx4 %1, %6, off\n\t"                                  \
      "global_load_dwordx4 %2, %7, off\n\t"                                  \
      "global_load_dwordx4 %3, %8, off\n\t"                                  \
      "global_load_dwordx4 %4, %9, off\n\t"                                  \
      "s_waitcnt vmcnt(0)"                                                   \
      : "=&v"(V0), "=&v"(V1), "=&v"(V2), "=&v"(V3), "=&v"(V4)                \
      : "v"(P0), "v"(P1), "v"(P2), "v"(P3), "v"(P4)                          \
      : "memory")

  // store one float4 (rows 4tx..4tx+3, col b) into swizzled tile
#define ST4(VV, BB)                                                          \
  {                                                                          \
    int cb = (BB) ^ tx;                                                      \
    int o  = (tx << 2) * TPADS + cb;                                         \
    tile[o            ] = f2h((VV)[0]);                                      \
    tile[o +     TPADS] = f2h((VV)[1]);                                      \
    tile[o + 2 * TPADS] = f2h((VV)[2]);                                      \
    tile[o + 3 * TPADS] = f2h((VV)[3]);                                      \
  }

  {
    f32x4 u0, u1, u2, u3, u4;
    LOAD5(u0, u1, u2, u3, u4,
          xp + (size_t)(bl      ) * COLS, xp + (size_t)(bl + 16) * COLS,
          xp + (size_t)(bl + 32) * COLS,  xp + (size_t)(bl + 48) * COLS,
          xp + (size_t)(bl + 64) * COLS);
    ST4(u0, bl)  ST4(u1, bl + 16)  ST4(u2, bl + 32)
    ST4(u3, bl + 48)  ST4(u4, bl + 64)
  }
  {
    f32x4 u0, u1, u2, u3, u4;
    LOAD5(u0, u1, u2, u3, u4,
          xp + (size_t)(bl +  80) * COLS, xp + (size_t)(bl +  96) * COLS,
          xp + (size_t)(bl + 112) * COLS, xp + (size_t)(bl + 128) * COLS,
          xp + (size_t)(bl + 144) * COLS);
    ST4(u0, bl + 80)  ST4(u1, bl + 96)  ST4(u2, bl + 112)
    ST4(u3, bl + 128) ST4(u4, bl + 144)
  }
  {
    const int b12 = (bl + 192 < B_) ? bl + 192 : B_ - 1;  // clamp
    f32x4 u0, u1, u2;
    asm volatile(
        "global_load_dwordx4 %0, %3, off\n\t"
        "global_load_dwordx4 %1, %4, off\n\t"
        "global_load_dwordx4 %2, %5, off\n\t"
        "s_waitcnt vmcnt(0)"
        : "=&v"(u0), "=&v"(u1), "=&v"(u2)
        : "v"(xp + (size_t)(bl + 160) * COLS),
          "v"(xp + (size_t)(bl + 176) * COLS),
          "v"(xp + (size_t)b12 * COLS)
        : "memory");
    ST4(u0, bl + 160)  ST4(u1, bl + 176)
    if (bl < 8) ST4(u2, bl + 192)
  }
#undef ST4
#undef LOAD5

  __syncthreads();
  // 128 rows x 50 uint2 = 6400 dense 8B stores (400B/row); unswizzle reads
#pragma unroll
  for (int q = 0; q < 13; ++q) {
    unsigned idx = (unsigned)t + ((unsigned)q << 9);
    if (idx < 6400u) {
      unsigned row = idx / 50u;            // magic-mul
      unsigned b0  = (idx - row * 50u) << 2;
      unsigned r   = (row >> 2) & 31u;
      const unsigned short* tp = tile + row * TPADS;
      uint32_t u0 = tp[(b0    ) ^ r];
      uint32_t u1 = tp[(b0 + 1) ^ r];
      uint32_t u2 = tp[(b0 + 2) ^ r];
      uint32_t u3 = tp[(b0 + 3) ^ r];
      uint2 o;
      o.x = u0 | (u1 << 16);
      o.y = u2 | (u3 << 16);
      *(uint2*)(xT2 + (size_t)(j0 + row) * B_ + b0) = o;
    }
  }
}

// ---------------- layer-1 pool + BN + ReLU + dropout ----------------
__global__ __launch_bounds__(256) void pool1_bn_wave(
    const unsigned short* __restrict__ xT2, const int* __restrict__ src,
    const float* __restrict__ w, const float* __restrict__ bias,
    const int* __restrict__ rp, const float* __restrict__ gamma,
    const float* __restrict__ beta, unsigned short* __restrict__ out,
    uint32_t k0, uint32_t k1) {
  __shared__ float part[2][64][4];
  const int l    = threadIdx.x & 63;
  const int wid  = threadIdx.x >> 6;
  const int chl  = wid & 1;
  const int half = wid >> 1;
  const int c    = ((int)blockIdx.x << 1) + chl;
  const bool act = (l < 50);
  const int b4   = (act ? l : 0) << 2;     // batches b4..b4+3

  float a0 = 0.f, a1 = 0.f, a2 = 0.f, a3 = 0.f;
  const int e1 = rp[c + 1];
  int e = rp[c] + half;
#define P1_EDGE(EE)                                                          \
  {                                                                          \
    const unsigned short* base = xT2 + (size_t)src[EE] * (3 * B_) + b4;      \
    float w0 = w[3 * (EE)], w1 = w[3 * (EE) + 1], w2 = w[3 * (EE) + 2];      \
    uint2 p0 = *(const uint2*)(base);                                        \
    uint2 p1 = *(const uint2*)(base + B_);                                   \
    uint2 p2 = *(const uint2*)(base + 2 * B_);                               \
    a0 = fmaf(h2f((unsigned short)p0.x), w0, a0);                            \
    a1 = fmaf(h2f((unsigned short)(p0.x >> 16)), w0, a1);                    \
    a2 = fmaf(h2f((unsigned short)p0.y), w0, a2);                            \
    a3 = fmaf(h2f((unsigned short)(p0.y >> 16)), w0, a3);                    \
    a0 = fmaf(h2f((unsigned short)p1.x), w1, a0);                            \
    a1 = fmaf(h2f((unsigned short)(p1.x >> 16)), w1, a1);                    \
    a2 = fmaf(h2f((unsigned short)p1.y), w1, a2);                            \
    a3 = fmaf(h2f((unsigned short)(p1.y >> 16)), w1, a3);                    \
    a0 = fmaf(h2f((unsigned short)p2.x), w2, a0);                            \
    a1 = fmaf(h2f((unsigned short)(p2.x >> 16)), w2, a1);                    \
    a2 = fmaf(h2f((unsigned short)p2.y), w2, a2);                            \
    a3 = fmaf(h2f((unsigned short)(p2.y >> 16)), w2, a3);                    \
  }
  for (; e + 2 < e1; e += 4) { P1_EDGE(e) P1_EDGE(e + 2) }
  for (; e < e1; e += 2) { P1_EDGE(e) }
#undef P1_EDGE

  if (half == 1) {
    part[chl][l][0] = a0; part[chl][l][1] = a1;
    part[chl][l][2] = a2; part[chl][l][3] = a3;
  }
  __syncthreads();
  if (half == 1) return;
  a0 += part[chl][l][0]; a1 += part[chl][l][1];
  a2 += part[chl][l][2]; a3 += part[chl][l][3];
  const float bi = bias[c];
  a0 += bi; a1 += bi; a2 += bi; a3 += bi;
  if (!act) { a0 = a1 = a2 = a3 = 0.f; }

  float sv = a0 + a1 + a2 + a3;
  float qv = a0 * a0 + a1 * a1 + a2 * a2 + a3 * a3;
#pragma unroll
  for (int off = 32; off; off >>= 1) {
    sv += __shfl_xor(sv, off);
    qv += __shfl_xor(qv, off);
  }
  const float m   = sv * (1.f / 200.f);
  const float var = fmaf(qv, 1.f / 200.f, -m * m);
  const float scale = gamma[c] * rsqrtf(var + 1e-5f);
  const float shift = fmaf(-m, scale, beta[c]);

  if (act) {
    float r0 = drop_mask_apply(fmaxf(fmaf(a0, scale, shift), 0.f), (uint32_t)b4,      (uint32_t)c, 16384u, k0, k1);
    float r1 = drop_mask_apply(fmaxf(fmaf(a1, scale, shift), 0.f), (uint32_t)b4 + 1u, (uint32_t)c, 16384u, k0, k1);
    float r2 = drop_mask_apply(fmaxf(fmaf(a2, scale, shift), 0.f), (uint32_t)b4 + 2u, (uint32_t)c, 16384u, k0, k1);
    float r3 = drop_mask_apply(fmaxf(fmaf(a3, scale, shift), 0.f), (uint32_t)b4 + 3u, (uint32_t)c, 16384u, k0, k1);
    uint2 pk;
    pk.x = (uint32_t)f2h(r0) | ((uint32_t)f2h(r1) << 16);
    pk.y = (uint32_t)f2h(r2) | ((uint32_t)f2h(r3) << 16);
    *(uint2*)(out + (size_t)c * B_ + b4) = pk;
  }
}

// ---------------- layers 2..5: 2 waves/channel, uint2 gathers ----------------
__global__ __launch_bounds__(256) void pooln_wave(
    const unsigned short* __restrict__ hin, const int* __restrict__ src,
    const float* __restrict__ w, const float* __restrict__ bias,
    const int* __restrict__ rp, const float* __restrict__ gamma,
    const float* __restrict__ beta, void* __restrict__ outv,
    int nout, int has_bn, uint32_t k0, uint32_t k1) {
  __shared__ float part[2][64][4];
  const int l    = threadIdx.x & 63;
  const int wid  = threadIdx.x >> 6;
  const int chl  = wid & 1;
  const int half = wid >> 1;
  const int c    = ((int)blockIdx.x << 1) + chl;
  const bool act = (l < 50);
  const int b4   = (act ? l : 0) << 2;

  float a0 = 0.f, a1 = 0.f, a2 = 0.f, a3 = 0.f;
  const int e1 = rp[c + 1];
  int e = rp[c] + half;
#define PN_EDGE(EE)                                                          \
  {                                                                          \
    const unsigned short* base = hin + (size_t)src[EE] * B_ + b4;            \
    float we = w[EE];                                                        \
    uint2 p0 = *(const uint2*)(base);                                        \
    a0 = fmaf(h2f((unsigned short)p0.x), we, a0);                            \
    a1 = fmaf(h2f((unsigned short)(p0.x >> 16)), we, a1);                    \
    a2 = fmaf(h2f((unsigned short)p0.y), we, a2);                            \
    a3 = fmaf(h2f((unsigned short)(p0.y >> 16)), we, a3);                    \
  }
  for (; e + 2 < e1; e += 4) { PN_EDGE(e) PN_EDGE(e + 2) }
  for (; e < e1; e += 2) { PN_EDGE(e) }
#undef PN_EDGE

  if (half == 1) {
    part[chl][l][0] = a0; part[chl][l][1] = a1;
    part[chl][l][2] = a2; part[chl][l][3] = a3;
  }
  __syncthreads();
  if (half == 1) return;
  a0 += part[chl][l][0]; a1 += part[chl][l][1];
  a2 += part[chl][l][2]; a3 += part[chl][l][3];
  const float bi = bias[c];
  a0 += bi; a1 += bi; a2 += bi; a3 += bi;

  if (has_bn) {
    if (!act) { a0 = a1 = a2 = a3 = 0.f; }
    float sv = a0 + a1 + a2 + a3;
    float qv = a0 * a0 + a1 * a1 + a2 * a2 + a3 * a3;
#pragma unroll
    for (int off = 32; off; off >>= 1) {
      sv += __shfl_xor(sv, off);
      qv += __shfl_xor(qv, off);
    }
    const float m   = sv * (1.f / 200.f);
    const float var = fmaf(qv, 1.f / 200.f, -m * m);
    const float scale = gamma[c] * rsqrtf(var + 1e-5f);
    const float shift = fmaf(-m, scale, beta[c]);
    if (act) {
      unsigned short* out = (unsigned short*)outv;
      uint32_t no = (uint32_t)nout;
      float r0 = drop_mask_apply(fmaxf(fmaf(a0, scale, shift), 0.f), (uint32_t)b4,      (uint32_t)c, no, k0, k1);
      float r1 = drop_mask_apply(fmaxf(fmaf(a1, scale, shift), 0.f), (uint32_t)b4 + 1u, (uint32_t)c, no, k0, k1);
      float r2 = drop_mask_apply(fmaxf(fmaf(a2, scale, shift), 0.f), (uint32_t)b4 + 2u, (uint32_t)c, no, k0, k1);
      float r3 = drop_mask_apply(fmaxf(fmaf(a3, scale, shift), 0.f), (uint32_t)b4 + 3u, (uint32_t)c, no, k0, k1);
      uint2 pk;
      pk.x = (uint32_t)f2h(r0) | ((uint32_t)f2h(r1) << 16);
      pk.y = (uint32_t)f2h(r2) | ((uint32_t)f2h(r3) << 16);
      *(uint2*)(out + (size_t)c * B_ + b4) = pk;
    }
  } else if (act) {
    float* out = (float*)outv;             // (B, 64) f32 final output
    out[(size_t)(b4    ) * 64 + c] = a0;
    out[(size_t)(b4 + 1) * 64 + c] = a1;
    out[(size_t)(b4 + 2) * 64 + c] = a2;
    out[(size_t)(b4 + 3) * 64 + c] = a3;
  }
}

// ---------------- host ----------------
extern "C" void kernel_launch(void* const* d_in, const int* in_sizes, int n_in,
                              void* d_out, int out_size, void* d_ws, size_t ws_size,
                              hipStream_t stream) {
  (void)in_sizes; (void)n_in; (void)out_size; (void)ws_size;
  const float* x = (const float*)d_in[0];
  const int*   src[5]; const int* dst[5];
  const float* w[5];   const float* bias[5];
  const float* gamma[4]; const float* beta[4];
  int idx = 1;
  for (int l = 0; l < 5; ++l) {
    src[l]  = (const int*)d_in[idx++];
    dst[l]  = (const int*)d_in[idx++];
    w[l]    = (const float*)d_in[idx++];
    bias[l] = (const float*)d_in[idx++];
    if (l < 4) { gamma[l] = (const float*)d_in[idx++]; beta[l] = (const float*)d_in[idx++]; }
  }
  static const int NOUT[5] = {16384, 4096, 1024, 256, 64};

  // dkeys = jax.random.split(key(42), 4), partitionable threefry semantics
  uint32_t dk0[4], dk1[4];
  for (uint32_t i = 0; i < 4; ++i) tf2x32(0u, 42u, 0u, i, dk0[i], dk1[i]);

  // workspace carve
  char* ws = (char*)d_ws;
  size_t off = 0;
  auto carve = [&](size_t bytes) -> void* {
    void* p = ws + off;
    off = (off + bytes + 255) & ~(size_t)255;
    return p;
  };
  int* rp[5];
  for (int l = 0; l < 5; ++l) rp[l] = (int*)carve((size_t)(NOUT[l] + 1) * sizeof(int));
  unsigned short* h1 = (unsigned short*)carve((size_t)16384 * B_ * 2);
  unsigned short* h2 = (unsigned short*)carve((size_t)4096 * B_ * 2);
  unsigned short* h3 = (unsigned short*)carve((size_t)1024 * B_ * 2);
  unsigned short* h4 = (unsigned short*)carve((size_t)256 * B_ * 2);
  unsigned short* xT2 = (unsigned short*)carve((size_t)COLS * B_ * 2);

  float* kl = (float*)d_out + 12800;

  // 0: zero the KL accumulator (graph-capture-safe async memset)
  hipMemsetAsync(kl, 0, sizeof(float), stream);

  // 1: transpose + row-ptrs + KL in one launch
  transpose_aux_kernel<<<NTB + RPB + KLB, 512, 0, stream>>>(
      x, xT2,
      dst[0], dst[1], dst[2], dst[3], dst[4],
      rp[0], rp[1], rp[2], rp[3], rp[4],
      w[0], w[1], w[2], w[3], w[4], kl);

  // 2: layer 1 — 2 waves/channel -> fp16 h1
  pool1_bn_wave<<<16384 / 2, 256, 0, stream>>>(
      xT2, src[0], w[0], bias[0], rp[0], gamma[0], beta[0], h1,
      dk0[0], dk1[0]);

  // 3-6: layers 2..5 — 2 waves/channel, fp16 chain
  pooln_wave<<<4096 / 2, 256, 0, stream>>>(
      h1, src[1], w[1], bias[1], rp[1], gamma[1], beta[1], h2, 4096, 1,
      dk0[1], dk1[1]);
  pooln_wave<<<1024 / 2, 256, 0, stream>>>(
      h2, src[2], w[2], bias[2], rp[2], gamma[2], beta[2], h3, 1024, 1,
      dk0[2], dk1[2]);
  pooln_wave<<<256 / 2, 256, 0, stream>>>(
      h3, src[3], w[3], bias[3], rp[3], gamma[3], beta[3], h4, 256, 1,
      dk0[3], dk1[3]);
  pooln_wave<<<64 / 2, 256, 0, stream>>>(
      h4, src[4], w[4], bias[4], rp[4], nullptr, nullptr, (float*)d_out, 64, 0,
      0u, 0u);
}